// Round 1
// baseline (189.505 us; speedup 1.0000x reference)
//
#include <hip/hip_runtime.h>

// Problem constants (from reference):
//   x:      (M=4, T=1024, F=512) fp32
//   conv_w: (OUT_CH=12288, 1, CK=3) fp32
//   conv_b: (OUT_CH=12288,) fp32
//   out:    (F=512, T=1024, L*M=12, K=8) fp32  -> 50,331,648 elements
//
// out[f, t, l*M+m, k]:
//   s  = k + l
//   if (t < s) -> 0
//   fs = (f - s) & 511                 (roll along feature axis)
//   o  = fs*24 + k*3 + l               (grouped-conv output channel)
//   val = b[o] + sum_{j=0..2} w[o*3+j] * x[m, t-2+j, fs]   (time taps clamped to >=0)

#define NF 512
#define NT 1024
#define NM 4
#define NK 8
#define NL 3
#define NLM 12   // L*M

__global__ __launch_bounds__(256) void caconv_kernel(
    const float* __restrict__ x,   // [M][T][F]
    const float* __restrict__ w,   // [12288][3]
    const float* __restrict__ b,   // [12288]
    float* __restrict__ out,       // [F][T][12][8]
    int total4)
{
    int idx = blockIdx.x * blockDim.x + threadIdx.x;
    const int stride = gridDim.x * blockDim.x;

    for (; idx < total4; idx += stride) {
        const int e   = idx << 2;          // first flat output element
        const int k0  = e & 7;             // 0 or 4 (4 | k0 pattern)
        const int rem = e >> 3;            // over (f, t, lm)
        const int lm  = rem % NLM;
        const int ft  = rem / NLM;
        const int t   = ft & (NT - 1);
        const int f   = ft >> 10;          // / NT
        const int l   = lm >> 2;           // lm / M
        const int m   = lm & 3;            // lm % M

        const float* xb = x + ((size_t)(m * NT + t) * NF);  // x[m][t][0]

        float r[4];
#pragma unroll
        for (int kk = 0; kk < 4; ++kk) {
            const int k = k0 + kk;
            const int s = k + l;
            float v = 0.0f;
            if (t >= s) {
                const int fs = (f - s) & (NF - 1);
                const int o  = fs * 24 + k * 3 + l;
                const float* wp = w + o * 3;
                float acc = b[o];
                if (t >= 2) {
                    acc += wp[0] * xb[fs - 2 * NF];
                    acc += wp[1] * xb[fs - NF];
                    acc += wp[2] * xb[fs];
                } else {
                    if (t >= 2) acc += wp[0] * xb[fs - 2 * NF];
                    if (t >= 1) acc += wp[1] * xb[fs - NF];
                    acc += wp[2] * xb[fs];
                }
                v = acc;
            }
            r[kk] = v;
        }
        float4 res = make_float4(r[0], r[1], r[2], r[3]);
        reinterpret_cast<float4*>(out)[idx] = res;
    }
}

extern "C" void kernel_launch(void* const* d_in, const int* in_sizes, int n_in,
                              void* d_out, int out_size, void* d_ws, size_t ws_size,
                              hipStream_t stream)
{
    const float* x = (const float*)d_in[0];
    const float* w = (const float*)d_in[1];
    const float* b = (const float*)d_in[2];
    float* out = (float*)d_out;

    const int total4 = out_size / 4;   // 12,582,912 float4 stores
    const int block = 256;
    const int grid = 8192;             // grid-stride, ~6 iters/thread

    caconv_kernel<<<grid, block, 0, stream>>>(x, w, b, out, total4);
}

// Round 2
// 54.386 us; speedup vs baseline: 3.4845x; 3.4845x over previous
//
#include <hip/hip_runtime.h>

// out[f, t, lm, k] (F=512, T=1024, LM=12, K=8) fp32:
//   l = lm/4, m = lm%4, s = k+l
//   t < s -> 0
//   fs = (f - s) & 511
//   o  = fs*24 + k*3 + l
//   val = b[o] + sum_{tap=0..2} w[o*3+tap] * x[m, t-2+tap, fs]  (t-2+tap < 0 -> 0)
//
// Block = (one f, one 64-wide t-chunk). Stage into LDS:
//   x_lds[m][tt][fi]  : tt in [0,66) <-> global t = t0-2+tt ; fi in [0,11) <-> fs = f-10+fi
//   w_lds[i=kl*3+tap] = w[fs(kl)*72 + i]   (72 floats: one channel per (k,l))
//   b_lds[kl]         = b[fs(kl)*24 + kl]  (24 floats)
// Each thread computes 3 "units" (unit = one (t,lm), all 8 k) -> 2 float4 stores each,
// fully coalesced across the block. All LDS compute reads use base+constant offsets.

#define NF 512
#define NT 1024
#define TT 64
#define XROW 12              // fi padded 11 -> 12
#define XM ((TT + 2) * XROW) // per-m stride in x_lds

__global__ __launch_bounds__(256) void caconv_kernel(
    const float* __restrict__ x,   // [4][1024][512]
    const float* __restrict__ w,   // [12288*3]
    const float* __restrict__ b,   // [12288]
    float* __restrict__ out)       // [512][1024][12][8]
{
    __shared__ float x_lds[4 * XM];   // 3168 floats
    __shared__ float w_lds[72];
    __shared__ float b_lds[24];

    const int tid = threadIdx.x;
    const int f   = blockIdx.x >> 4;
    const int t0  = (blockIdx.x & 15) * TT;

    // ---- stage weights / bias (96 threads) ----
    if (tid < 72) {
        const int kl = tid / 3;              // k*3 + l
        const int s  = kl / 3 + kl % 3;      // k + l
        const int fs = (f - s) & (NF - 1);
        w_lds[tid] = w[fs * 72 + tid];
    } else if (tid < 96) {
        const int kl = tid - 72;
        const int s  = kl / 3 + kl % 3;
        const int fs = (f - s) & (NF - 1);
        b_lds[kl] = b[fs * 24 + kl];
    }

    // ---- stage x slab: 4 * 66 * 11 = 2904 floats ----
    for (int i = tid; i < 4 * (TT + 2) * 11; i += 256) {
        const int m  = i / ((TT + 2) * 11);
        const int r  = i - m * ((TT + 2) * 11);
        const int tt = r / 11;
        const int fi = r - tt * 11;
        const int tg = t0 - 2 + tt;
        const int fs = (f - 10 + fi) & (NF - 1);
        float v = 0.0f;
        if (tg >= 0) v = x[(((m << 10) + tg) << 9) + fs];
        x_lds[m * XM + tt * XROW + fi] = v;
    }
    __syncthreads();

    // ---- compute: 768 units, 3 per thread ----
#pragma unroll
    for (int j = 0; j < 3; ++j) {
        const int u     = tid + j * 256;     // < 768
        const int t_off = u / 12;
        const int lm    = u - t_off * 12;
        const int l     = lm >> 2;
        const int m     = lm & 3;
        const int t     = t0 + t_off;

        // xp points at fi = 3-l of row tt = t_off (global time t-2)
        const float* xp = x_lds + m * XM + t_off * XROW + (3 - l);
        const float* wp = w_lds + l * 3;     // wp[k*9+tap] = w2[k,l,tap]
        const float* bp = b_lds + l;         // bp[k*3]     = b2[k,l]

        float acc[8];
#pragma unroll
        for (int k = 0; k < 8; ++k) acc[k] = bp[k * 3];

#pragma unroll
        for (int tap = 0; tap < 3; ++tap) {
            const float* p = xp + tap * XROW;   // row tt = t_off+tap <-> time t-2+tap
#pragma unroll
            for (int k = 0; k < 8; ++k)
                acc[k] += wp[k * 9 + tap] * p[7 - k];   // fi = 10-(k+l)
        }

        if (t < 10) {
#pragma unroll
            for (int k = 0; k < 8; ++k)
                if (t < k + l) acc[k] = 0.0f;
        }

        float* o = out + ((size_t)((f << 10) + t) * 12 + lm) * 8;
        *reinterpret_cast<float4*>(o)     = make_float4(acc[0], acc[1], acc[2], acc[3]);
        *reinterpret_cast<float4*>(o + 4) = make_float4(acc[4], acc[5], acc[6], acc[7]);
    }
}

extern "C" void kernel_launch(void* const* d_in, const int* in_sizes, int n_in,
                              void* d_out, int out_size, void* d_ws, size_t ws_size,
                              hipStream_t stream)
{
    const float* x = (const float*)d_in[0];
    const float* w = (const float*)d_in[1];
    const float* b = (const float*)d_in[2];
    float* out = (float*)d_out;

    const int grid = NF * (NT / TT);   // 512 * 16 = 8192 blocks
    caconv_kernel<<<grid, 256, 0, stream>>>(x, w, b, out);
}